// Round 10
// baseline (151.183 us; speedup 1.0000x reference)
//
#include <hip/hip_runtime.h>
#include <hip/hip_fp8.h>
#include <math.h>

// ContrastiveLoss — x (8,128,16,8,8) fp32 (4 MB).
// feats[n,f] = x[b*131072 + f*1024 + r], n=(b<<10)|r, N=8192, F=128.
// loss = 10 + ln( sum_{i!=j} exp(10*dot(x̂_i,x̂_j) - 10) )   (unit rows => s<=10)
//
// Round 19: MEASUREMENT ROUND #3 (early-window clock + LDS-gram counters).
// R18 result: LDS macro-tile gram = 16.9 µs (only -1.4), vs 5-9 µs cycle
// model. The 2-3x residual is either (b) low gfxclk early in the window
// (R8's 1.35 GHz probe ran LAST, after ~100µs of core activity) or (c) a
// genuine stall. Opposite remedies -> measure before touching anything:
//  * clock_probe FIRST: 16384 dependent FMAs = 65536 cyc, clock-invariant.
//    27 µs @2.4GHz / 48 @1.35 / 90 @0.7. Surfaces in top-5 if >=~41 µs.
//  * gram GREPS=6 (carry idiom, rep-end barrier): dispatch ~40-50 µs ->
//    surfaces VGPR/WRITE_SIZE/MfmaUtil/VALUBusy/Occupancy; warm rep time
//    w = (dur-16.9)/5 splits cold-miss cost from steady-state cost.
// Gram body is byte-identical to R18; both instruments reverted next round.
//
// fp8 swizzled layout (verified R7/R8, absmax 0): row-group rg=n>>4 (16 rows,
// 2KB). 16B chunk (t8*64 + q*16 + r) holds bytes[half*8+j] =
// x̂[row r][k = t8*64 + half*32 + q*8 + j]. C/D: col=lane&15,
// row=(lane>>4)*4+reg (dtype-independent, verified).
//
// ws: partials float[2080] @0; probe scratch @16384B; Xs fp8 @131072 (1MB).

#define NMACR 2080   // 64*65/2 upper-triangle 128x128 macro-tiles
#define GREPS 6      // gram measurement multiplier (revert to 1 after)

typedef __attribute__((ext_vector_type(4))) float f32x4;
typedef __attribute__((ext_vector_type(2))) long i64x2;

#if __has_builtin(__builtin_amdgcn_exp2f)
#define EXP2F(x) __builtin_amdgcn_exp2f(x)
#else
#define EXP2F(x) exp2f(x)
#endif

__device__ inline unsigned int pk_fp8(float f0, float f1, float f2, float f3) {
#if __has_builtin(__builtin_amdgcn_cvt_pk_fp8_f32)
    unsigned int r = 0;
    r = __builtin_amdgcn_cvt_pk_fp8_f32(f0, f1, r, false);  // bytes 0,1
    r = __builtin_amdgcn_cvt_pk_fp8_f32(f2, f3, r, true);   // bytes 2,3
    return r;
#else
    union { unsigned char b[4]; unsigned int u; } v;
    v.b[0] = __hip_fp8_e4m3(f0).__x; v.b[1] = __hip_fp8_e4m3(f1).__x;
    v.b[2] = __hip_fp8_e4m3(f2).__x; v.b[3] = __hip_fp8_e4m3(f3).__x;
    return v.u;
#endif
}

// ---------------------------------------------------------------------------
// Clock probe: 1 wave, 16384 strictly dependent fmaf (4 cyc latency each ->
// 65536-cycle chain, clock-invariant). Launched FIRST: reads EARLY-window
// gfxclk. Writes to unused ws slot to stay live.
// ---------------------------------------------------------------------------
__global__ __launch_bounds__(64)
void clock_probe(const float* __restrict__ x, float* __restrict__ scratch) {
    float a = x[threadIdx.x] * 1e-38f + 0.999999f;   // ~1, data-dependent
    float b = 0.f;
    for (int i = 0; i < 1024; ++i) {
#pragma unroll
        for (int j = 0; j < 16; ++j) b = fmaf(b, a, 1.0f);  // dependent chain
    }
    scratch[threadIdx.x] = b;                         // keep live
}

// ---------------------------------------------------------------------------
// Kernel 1: normalize + fp8 swizzle. Block = 32 rows (2 row-groups).
// ---------------------------------------------------------------------------
__global__ __launch_bounds__(256)
void normalize_kernel(const float* __restrict__ x, unsigned char* __restrict__ Xs) {
    __shared__ float ldsf[128][33];
    __shared__ float ssred[8][32];
    __shared__ float invs[32];
    const int tid = threadIdx.x;
    const int b  = blockIdx.x >> 5;
    const int r0 = (blockIdx.x & 31) * 32;
    const int rl = tid & 31, fp = tid >> 5;       // row-in-block, f-slot
    const float* px = x + b * 131072 + r0 + rl;
    float ss = 0.f;
#pragma unroll
    for (int j = 0; j < 16; ++j) {
        int f = fp * 16 + j;
        float v = px[f * 1024];
        ldsf[f][rl] = v;
        ss = fmaf(v, v, ss);
    }
    ssred[fp][rl] = ss;
    __syncthreads();
    if (tid < 32) {
        float s = 0.f;
#pragma unroll
        for (int k = 0; k < 8; ++k) s += ssred[k][tid];
        invs[tid] = 1.0f / fmaxf(sqrtf(s), 1e-12f);
    }
    __syncthreads();
    {   // one 16B chunk per thread, consecutive tid -> consecutive chunks
        const int c   = tid;
        const int rgl = c >> 7;                   // local row-group 0..1
        const int cc  = c & 127;                  // chunk within row-group
        const int t8  = (cc >> 6) & 1, q = (cc >> 4) & 3, r = cc & 15;
        const int row = rgl * 16 + r;             // local row 0..31
        const float inv = invs[row];
        union { unsigned int w[4]; int4 v; } u;
#pragma unroll
        for (int half = 0; half < 2; ++half) {
            const int k0 = t8 * 64 + half * 32 + q * 8;
            u.w[half * 2 + 0] = pk_fp8(ldsf[k0 + 0][row] * inv, ldsf[k0 + 1][row] * inv,
                                       ldsf[k0 + 2][row] * inv, ldsf[k0 + 3][row] * inv);
            u.w[half * 2 + 1] = pk_fp8(ldsf[k0 + 4][row] * inv, ldsf[k0 + 5][row] * inv,
                                       ldsf[k0 + 6][row] * inv, ldsf[k0 + 7][row] * inv);
        }
        const int rgg = blockIdx.x * 2 + rgl;     // global row-group
        ((int4*)Xs)[rgg * 128 + cc] = u.v;
    }
}

// ---------------------------------------------------------------------------
// Kernel 2: R18 LDS macro-tile gram, repeated `reps` times (carry idiom:
// data-dependent 0 offsets the Xs base; rep-end barrier so re-staging can't
// race the previous rep's LDS reads). Body identical to R18.
// ---------------------------------------------------------------------------
__global__ __launch_bounds__(256)
void gram_lse_kernel(const i64x2* __restrict__ Xs0, float* __restrict__ partials,
                     int reps) {
    const int bk = blockIdx.x;
    const int tid = threadIdx.x;
    const int lane = tid & 63, w = tid >> 6;
    const int ga = (w & 1) * 2;                  // A rg offset within sub-tile
    const int gb = (w >> 1) * 2;                 // B rg offset within sub-tile
    const int quad = lane >> 4, colL = lane & 15;
    const float C = 14.426950408889634f;         // 10*log2(e)

    // closed-form macro decode: tiles_before(I) = I*(129-I)/2  (64 rows)
    int I;
    {
        const int t = bk;
        I = (int)((129.0 - sqrt(16641.0 - 8.0 * (double)t)) * 0.5);
        if (I < 0) I = 0;
        while ((((I + 1) * (128 - I)) >> 1) <= t) ++I;   // tb(I+1) <= t
        while (((I * (129 - I)) >> 1) > t) --I;          // tb(I)   >  t
    }
    const int J = I + (bk - ((I * (129 - I)) >> 1));
    const bool diagM = (I == J);

    __shared__ i64x2 ldsA[1024];                 // 16KB: A panel (8 rgs)
    __shared__ i64x2 ldsB[1024];                 // 16KB: B panel (8 rgs)

    float wsum = 0.f;
    int carry = 0;                                // always 0, data-dependent
    for (int rep = 0; rep < reps; ++rep) {
        const i64x2* __restrict__ Xs = Xs0 + carry;
        wsum = 0.f;
        {
            const i64x2* pa = Xs + I * 1024;     // panel = contiguous Xs slice
            if (diagM) {
#pragma unroll
                for (int i = 0; i < 4; ++i)
                    ldsA[tid + i * 256] = pa[tid + i * 256];
            } else {
                const i64x2* pb = Xs + J * 1024;
#pragma unroll
                for (int i = 0; i < 4; ++i) {
                    ldsA[tid + i * 256] = pa[tid + i * 256];
                    ldsB[tid + i * 256] = pb[tid + i * 256];
                }
            }
        }
        __syncthreads();
        const i64x2* lb = diagM ? ldsA : ldsB;

        // A fragments for both row sub-tiles, register-resident
        i64x2 avv[2][2][2];
#pragma unroll
        for (int ti = 0; ti < 2; ++ti)
#pragma unroll
            for (int g = 0; g < 2; ++g)
#pragma unroll
                for (int t8 = 0; t8 < 2; ++t8)
                    avv[ti][g][t8] = ldsA[(ti * 4 + ga + g) * 128 + t8 * 64 + lane];

#pragma unroll
        for (int tj = 0; tj < 2; ++tj) {
            i64x2 bvv[2][2];
#pragma unroll
            for (int g = 0; g < 2; ++g)
#pragma unroll
                for (int t8 = 0; t8 < 2; ++t8)
                    bvv[g][t8] = lb[(tj * 4 + gb + g) * 128 + t8 * 64 + lane];

#pragma unroll
            for (int ti = 0; ti < 2; ++ti) {
                if (diagM && ti > tj) continue;  // below-diagonal sub: skip
                const bool dsub = diagM && (ti == tj);

                f32x4 acc[2][2];
#pragma unroll
                for (int i = 0; i < 2; ++i)
#pragma unroll
                    for (int j = 0; j < 2; ++j) acc[i][j] = (f32x4){0.f, 0.f, 0.f, 0.f};
#pragma unroll
                for (int t = 0; t < 4; ++t) {    // K-steps of 32
                    const int th = t >> 1, tl = t & 1;
                    long aL[2], bL[2];
#pragma unroll
                    for (int g = 0; g < 2; ++g) {
                        aL[g] = avv[ti][g][th][tl];
                        bL[g] = bvv[g][th][tl];
                    }
#pragma unroll
                    for (int i = 0; i < 2; ++i)
#pragma unroll
                        for (int j = 0; j < 2; ++j)
                            acc[i][j] = __builtin_amdgcn_mfma_f32_16x16x32_fp8_fp8(
                                aL[i], bL[j], acc[i][j], 0, 0, 0);
                }

                // C/D: col=lane&15, row=(lane>>4)*4+reg (verified)
                float lsum = 0.f;
#pragma unroll
                for (int i = 0; i < 2; ++i) {
                    const int rbase = (ga + i) * 16 + quad * 4;
#pragma unroll
                    for (int j = 0; j < 2; ++j) {
                        const int cbase = (gb + j) * 16 + colL;
#pragma unroll
                        for (int g = 0; g < 4; ++g) {
                            if (dsub && (rbase + g == cbase)) continue;
                            lsum += EXP2F(fmaf(C, acc[i][j][g], -C));
                        }
                    }
                }
                wsum += dsub ? lsum : 2.0f * lsum;   // symmetry weight
            }
        }
        carry = (int)(wsum * 0.0f);               // 0, depends on this rep
        __syncthreads();                          // rep boundary (staging race)
    }

#pragma unroll
    for (int o = 32; o > 0; o >>= 1) wsum += __shfl_down(wsum, o, 64);
    __shared__ float red[4];
    if (lane == 0) red[w] = wsum;
    __syncthreads();
    if (tid == 0) partials[bk] = red[0] + red[1] + red[2] + red[3];
}

// ---------------------------------------------------------------------------
// Kernel 3: out = 10 + ln(sum of 2080 partials), f64 accumulation.
// ---------------------------------------------------------------------------
__global__ __launch_bounds__(256)
void final_kernel(const float* __restrict__ partials, float* __restrict__ out) {
    double s = 0.0;
    for (int i = threadIdx.x; i < NMACR; i += 256) s += (double)partials[i];
#pragma unroll
    for (int o = 32; o > 0; o >>= 1) s += __shfl_down(s, o, 64);
    __shared__ double red[4];
    if ((threadIdx.x & 63) == 0) red[threadIdx.x >> 6] = s;
    __syncthreads();
    if (threadIdx.x == 0)
        out[0] = (float)(10.0 + log(red[0] + red[1] + red[2] + red[3]));
}

extern "C" void kernel_launch(void* const* d_in, const int* in_sizes, int n_in,
                              void* d_out, int out_size, void* d_ws, size_t ws_size,
                              hipStream_t stream) {
    const float* x = (const float*)d_in[0];
    float* out = (float*)d_out;
    float* partials = (float*)d_ws;                         // 2080 floats
    float* probe_scr = (float*)((char*)d_ws + 16384);       // unused by final
    unsigned char* Xs = (unsigned char*)d_ws + 131072;      // 1MB fp8 X̂

    clock_probe<<<1, 64, 0, stream>>>(x, probe_scr);        // EARLY-window clock
    normalize_kernel<<<256, 256, 0, stream>>>(x, Xs);
    gram_lse_kernel<<<NMACR, 256, 0, stream>>>((const i64x2*)Xs, partials, GREPS);
    final_kernel<<<1, 256, 0, stream>>>(partials, out);
}

// Round 11
// 68.135 us; speedup vs baseline: 2.2189x; 2.2189x over previous
//
#include <hip/hip_runtime.h>
#include <hip/hip_fp8.h>
#include <math.h>

// ContrastiveLoss — x (8,128,16,8,8) fp32 (4 MB).
// feats[n,f] = x[b*131072 + f*1024 + r], n=(b<<10)|r, N=8192, F=128.
// loss = 10 + ln( sum_{i!=j} exp(10*dot(x̂_i,x̂_j) - 10) )   (unit rows => s<=10)
//
// Round 20: HALVE LDS -> DOUBLE RESIDENT BLOCKS. R19 measurements:
//  * early gfxclk ~1.75 GHz (mild throttle); gram warm rep 8.7 µs
//    (VALU/TRANS-issue bound: VALUBusy 60%), cold premium 8.2 µs = pure
//    first-touch latency (FETCH 4.1MB, WRITE 65KB -> no spill, no BW issue).
//  * Occupancy 30%: 33 KB LDS caps 4 blocks/CU -> too few in-flight cold
//    misses chip-wide.
// Change (single): delete ldsA. Each wave's A fragments (avv, 32 VGPR) are
// private -> LDS relay was pure overhead; load avv straight from global
// (issues before the barrier, overlaps B staging). Only the B panel stays
// in LDS (shared by 2 waves/rg). LDS 33->16.6 KB: 8+ blocks/CU co-resident,
// whole grid stages at once -> chip-wide MLP hides cold latency.
//
// fp8 swizzled layout (verified R7/R8, absmax 0): row-group rg=n>>4 (16 rows,
// 2KB). 16B chunk (t8*64 + q*16 + r) holds bytes[half*8+j] =
// x̂[row r][k = t8*64 + half*32 + q*8 + j]. C/D: col=lane&15,
// row=(lane>>4)*4+reg (dtype-independent, verified).
//
// ws: partials float[2080] @0; Xs fp8[8192*128] @131072 (1MB).

#define NMACR 2080   // 64*65/2 upper-triangle 128x128 macro-tiles

typedef __attribute__((ext_vector_type(4))) float f32x4;
typedef __attribute__((ext_vector_type(2))) long i64x2;

#if __has_builtin(__builtin_amdgcn_exp2f)
#define EXP2F(x) __builtin_amdgcn_exp2f(x)
#else
#define EXP2F(x) exp2f(x)
#endif

__device__ inline unsigned int pk_fp8(float f0, float f1, float f2, float f3) {
#if __has_builtin(__builtin_amdgcn_cvt_pk_fp8_f32)
    unsigned int r = 0;
    r = __builtin_amdgcn_cvt_pk_fp8_f32(f0, f1, r, false);  // bytes 0,1
    r = __builtin_amdgcn_cvt_pk_fp8_f32(f2, f3, r, true);   // bytes 2,3
    return r;
#else
    union { unsigned char b[4]; unsigned int u; } v;
    v.b[0] = __hip_fp8_e4m3(f0).__x; v.b[1] = __hip_fp8_e4m3(f1).__x;
    v.b[2] = __hip_fp8_e4m3(f2).__x; v.b[3] = __hip_fp8_e4m3(f3).__x;
    return v.u;
#endif
}

// ---------------------------------------------------------------------------
// Kernel 1: normalize + fp8 swizzle. Block = 32 rows (2 row-groups).
// ---------------------------------------------------------------------------
__global__ __launch_bounds__(256)
void normalize_kernel(const float* __restrict__ x, unsigned char* __restrict__ Xs) {
    __shared__ float ldsf[128][33];
    __shared__ float ssred[8][32];
    __shared__ float invs[32];
    const int tid = threadIdx.x;
    const int b  = blockIdx.x >> 5;
    const int r0 = (blockIdx.x & 31) * 32;
    const int rl = tid & 31, fp = tid >> 5;       // row-in-block, f-slot
    const float* px = x + b * 131072 + r0 + rl;
    float ss = 0.f;
#pragma unroll
    for (int j = 0; j < 16; ++j) {
        int f = fp * 16 + j;
        float v = px[f * 1024];
        ldsf[f][rl] = v;
        ss = fmaf(v, v, ss);
    }
    ssred[fp][rl] = ss;
    __syncthreads();
    if (tid < 32) {
        float s = 0.f;
#pragma unroll
        for (int k = 0; k < 8; ++k) s += ssred[k][tid];
        invs[tid] = 1.0f / fmaxf(sqrtf(s), 1e-12f);
    }
    __syncthreads();
    {   // one 16B chunk per thread, consecutive tid -> consecutive chunks
        const int c   = tid;
        const int rgl = c >> 7;                   // local row-group 0..1
        const int cc  = c & 127;                  // chunk within row-group
        const int t8  = (cc >> 6) & 1, q = (cc >> 4) & 3, r = cc & 15;
        const int row = rgl * 16 + r;             // local row 0..31
        const float inv = invs[row];
        union { unsigned int w[4]; int4 v; } u;
#pragma unroll
        for (int half = 0; half < 2; ++half) {
            const int k0 = t8 * 64 + half * 32 + q * 8;
            u.w[half * 2 + 0] = pk_fp8(ldsf[k0 + 0][row] * inv, ldsf[k0 + 1][row] * inv,
                                       ldsf[k0 + 2][row] * inv, ldsf[k0 + 3][row] * inv);
            u.w[half * 2 + 1] = pk_fp8(ldsf[k0 + 4][row] * inv, ldsf[k0 + 5][row] * inv,
                                       ldsf[k0 + 6][row] * inv, ldsf[k0 + 7][row] * inv);
        }
        const int rgg = blockIdx.x * 2 + rgl;     // global row-group
        ((int4*)Xs)[rgg * 128 + cc] = u.v;
    }
}

// ---------------------------------------------------------------------------
// Kernel 2: macro-tile gram, B-only LDS. Block bk -> upper-tri macro (I,J),
// 128x128. avv (private A slices) loaded DIRECTLY from global; B panel
// (16KB, shared) staged in LDS; one barrier; 4 waves x 2x2 sub-tiles.
// ---------------------------------------------------------------------------
__global__ __launch_bounds__(256)
void gram_lse_kernel(const i64x2* __restrict__ Xs, float* __restrict__ partials) {
    const int bk = blockIdx.x;
    const int tid = threadIdx.x;
    const int lane = tid & 63, w = tid >> 6;
    const int ga = (w & 1) * 2;                  // A rg offset within sub-tile
    const int gb = (w >> 1) * 2;                 // B rg offset within sub-tile
    const int quad = lane >> 4, colL = lane & 15;
    const float C = 14.426950408889634f;         // 10*log2(e)

    // closed-form macro decode: tiles_before(I) = I*(129-I)/2  (64 rows)
    int I;
    {
        const int t = bk;
        I = (int)((129.0 - sqrt(16641.0 - 8.0 * (double)t)) * 0.5);
        if (I < 0) I = 0;
        while ((((I + 1) * (128 - I)) >> 1) <= t) ++I;   // tb(I+1) <= t
        while (((I * (129 - I)) >> 1) > t) --I;          // tb(I)   >  t
    }
    const int J = I + (bk - ((I * (129 - I)) >> 1));
    const bool diagM = (I == J);

    // A fragments: DIRECT global loads (private per wave; no LDS relay).
    // rg = 8I + ti*4 + ga + g
    i64x2 avv[2][2][2];
#pragma unroll
    for (int ti = 0; ti < 2; ++ti)
#pragma unroll
        for (int g = 0; g < 2; ++g)
#pragma unroll
            for (int t8 = 0; t8 < 2; ++t8)
                avv[ti][g][t8] =
                    Xs[(I * 8 + ti * 4 + ga + g) * 128 + t8 * 64 + lane];

    // B panel staged in LDS (shared: each rg read by 2 waves, twice)
    __shared__ i64x2 ldsB[1024];                 // 16KB: B panel (8 rgs)
    {
        const i64x2* pb = Xs + J * 1024;         // panel = contiguous Xs slice
#pragma unroll
        for (int i = 0; i < 4; ++i)
            ldsB[tid + i * 256] = pb[tid + i * 256];
    }
    __syncthreads();

    float wsum = 0.f;
#pragma unroll
    for (int tj = 0; tj < 2; ++tj) {
        i64x2 bvv[2][2];
#pragma unroll
        for (int g = 0; g < 2; ++g)
#pragma unroll
            for (int t8 = 0; t8 < 2; ++t8)
                bvv[g][t8] = ldsB[(tj * 4 + gb + g) * 128 + t8 * 64 + lane];

#pragma unroll
        for (int ti = 0; ti < 2; ++ti) {
            if (diagM && ti > tj) continue;      // below-diagonal sub: skip
            const bool dsub = diagM && (ti == tj);

            f32x4 acc[2][2];
#pragma unroll
            for (int i = 0; i < 2; ++i)
#pragma unroll
                for (int j = 0; j < 2; ++j) acc[i][j] = (f32x4){0.f, 0.f, 0.f, 0.f};
#pragma unroll
            for (int t = 0; t < 4; ++t) {        // K-steps of 32
                const int th = t >> 1, tl = t & 1;
                long aL[2], bL[2];
#pragma unroll
                for (int g = 0; g < 2; ++g) {
                    aL[g] = avv[ti][g][th][tl];
                    bL[g] = bvv[g][th][tl];
                }
#pragma unroll
                for (int i = 0; i < 2; ++i)
#pragma unroll
                    for (int j = 0; j < 2; ++j)
                        acc[i][j] = __builtin_amdgcn_mfma_f32_16x16x32_fp8_fp8(
                            aL[i], bL[j], acc[i][j], 0, 0, 0);
            }

            // C/D: col=lane&15, row=(lane>>4)*4+reg (verified)
            float lsum = 0.f;
#pragma unroll
            for (int i = 0; i < 2; ++i) {
                const int rbase = (ga + i) * 16 + quad * 4;   // row in sub-tile
#pragma unroll
                for (int j = 0; j < 2; ++j) {
                    const int cbase = (gb + j) * 16 + colL;   // col in sub-tile
#pragma unroll
                    for (int g = 0; g < 4; ++g) {
                        if (dsub && (rbase + g == cbase)) continue;
                        lsum += EXP2F(fmaf(C, acc[i][j][g], -C));
                    }
                }
            }
            wsum += dsub ? lsum : 2.0f * lsum;   // symmetry weight
        }
    }

#pragma unroll
    for (int o = 32; o > 0; o >>= 1) wsum += __shfl_down(wsum, o, 64);
    __shared__ float red[4];
    if (lane == 0) red[w] = wsum;
    __syncthreads();
    if (tid == 0) partials[bk] = red[0] + red[1] + red[2] + red[3];
}

// ---------------------------------------------------------------------------
// Kernel 3: out = 10 + ln(sum of 2080 partials), f64 accumulation.
// ---------------------------------------------------------------------------
__global__ __launch_bounds__(256)
void final_kernel(const float* __restrict__ partials, float* __restrict__ out) {
    double s = 0.0;
    for (int i = threadIdx.x; i < NMACR; i += 256) s += (double)partials[i];
#pragma unroll
    for (int o = 32; o > 0; o >>= 1) s += __shfl_down(s, o, 64);
    __shared__ double red[4];
    if ((threadIdx.x & 63) == 0) red[threadIdx.x >> 6] = s;
    __syncthreads();
    if (threadIdx.x == 0)
        out[0] = (float)(10.0 + log(red[0] + red[1] + red[2] + red[3]));
}

extern "C" void kernel_launch(void* const* d_in, const int* in_sizes, int n_in,
                              void* d_out, int out_size, void* d_ws, size_t ws_size,
                              hipStream_t stream) {
    const float* x = (const float*)d_in[0];
    float* out = (float*)d_out;
    float* partials = (float*)d_ws;                         // 2080 floats
    unsigned char* Xs = (unsigned char*)d_ws + 131072;      // 1MB fp8 X̂

    normalize_kernel<<<256, 256, 0, stream>>>(x, Xs);
    gram_lse_kernel<<<NMACR, 256, 0, stream>>>((const i64x2*)Xs, partials);
    final_kernel<<<1, 256, 0, stream>>>(partials, out);
}